// Round 7
// baseline (430.702 us; speedup 1.0000x reference)
//
#include <hip/hip_runtime.h>
#include <cmath>

#define B_    16
#define HH    56
#define WWI   56
#define C_    256
#define NH_   8
#define WS_   7
#define SS_   3
#define HD_   32
#define NN    49             // window size squared
#define SCALE_ 0.17677669529663689f
#define EPS_  1e-5f

typedef __bf16  bf16x8  __attribute__((ext_vector_type(8)));
typedef float   f32x4   __attribute__((ext_vector_type(4)));
typedef unsigned short ushort8v __attribute__((ext_vector_type(8)));

__device__ __forceinline__ unsigned short f2bf(float f) {
    unsigned int u = __float_as_uint(f);
    unsigned int r = u + 0x7FFFu + ((u >> 16) & 1u);   // RNE
    return (unsigned short)(r >> 16);
}
__device__ __forceinline__ float bf2f(unsigned short h) {
    return __uint_as_float(((unsigned int)h) << 16);
}
// tanh-form GELU: |err| <= ~3e-3 vs exact erf form; hw v_exp_f32 + rcp
__device__ __forceinline__ float gelu_t(float x) {
    float t = 0.7978845608028654f * (x + 0.044715f * x * x * x);
    float e = __expf(2.0f * t);
    float th = 1.0f - 2.0f * __builtin_amdgcn_rcpf(e + 1.0f);
    return 0.5f * x * (1.0f + th);
}

// async global->LDS DMA, 16B per lane; deposits at wave-uniform lds base + lane*16
__device__ __forceinline__ void gload_lds16(const unsigned short* g, unsigned short* l) {
    __builtin_amdgcn_global_load_lds(
        (const __attribute__((address_space(1))) unsigned int*)g,
        (__attribute__((address_space(3))) unsigned int*)l, 16, 0, 0);
}

// ---------------- weight fp32 -> bf16 conversion ----------------
__global__ __launch_bounds__(256) void convw_k(
    const float* __restrict__ qkvw, const float* __restrict__ projw,
    const float* __restrict__ fc1w, const float* __restrict__ fc2w,
    unsigned short* __restrict__ dst)
{
    int i = blockIdx.x * 256 + threadIdx.x;          // < 786432
    float v;
    if      (i < 196608) v = qkvw[i];
    else if (i < 262144) v = projw[i - 196608];
    else if (i < 524288) v = fc1w[i - 262144];
    else                 v = fc2w[i - 524288];
    dst[i] = f2bf(v);
}

// ---------------- combined rel-bias + shift-mask table, bf16 ----------------
__global__ __launch_bounds__(256) void cb_k(
    const float* __restrict__ mask, const float* __restrict__ relb,
    unsigned short* __restrict__ cb)
{
    int s = blockIdx.x;                 // 512 slices = 64 windows * 8 heads
    int wi = s >> 3, head = s & 7;
    for (int p = threadIdx.x; p < 2408; p += 256) {
        float v = 0.0f;
        if (p < 2401) {
            int i = p / NN, j = p - i * NN;
            int di = i / 7 - j / 7 + 6, dj = i % 7 - j % 7 + 6;
            v = relb[(di * 13 + dj) * NH_ + head] + mask[(size_t)wi * 2401 + p];
        }
        cb[(size_t)s * 2408 + p] = f2bf(v);
    }
}

// ---------------- LayerNorm (plain token order; used for LN2) ----------------
__global__ __launch_bounds__(256) void ln_k(
    const float* __restrict__ x, const float* __restrict__ g,
    const float* __restrict__ bta, unsigned short* __restrict__ dst)
{
    int wave = threadIdx.x >> 6, lane = threadIdx.x & 63;
    int tok = blockIdx.x * 4 + wave;                  // < 50176
    const float4 v = *(const float4*)(x + (size_t)tok * C_ + lane * 4);
    float s = v.x + v.y + v.z + v.w;
    float q = v.x*v.x + v.y*v.y + v.z*v.z + v.w*v.w;
    for (int o = 32; o > 0; o >>= 1) { s += __shfl_xor(s, o, 64); q += __shfl_xor(q, o, 64); }
    float mu  = s * (1.0f / C_);
    float var = q * (1.0f / C_) - mu * mu;
    float rs  = rsqrtf(var + EPS_);
    float4 gg = *(const float4*)(g   + lane * 4);
    float4 bb = *(const float4*)(bta + lane * 4);
    float y0 = (v.x - mu) * rs * gg.x + bb.x;
    float y1 = (v.y - mu) * rs * gg.y + bb.y;
    float y2 = (v.z - mu) * rs * gg.z + bb.z;
    float y3 = (v.w - mu) * rs * gg.w + bb.w;
    size_t di = (size_t)tok * C_ + lane * 4;
    unsigned int lo = (unsigned int)f2bf(y0) | ((unsigned int)f2bf(y1) << 16);
    unsigned int hi = (unsigned int)f2bf(y2) | ((unsigned int)f2bf(y3) << 16);
    uint2 u; u.x = lo; u.y = hi;
    *(uint2*)(dst + di) = u;
}

// ====== MEGA: LN1 + shift/window gather + QKV GEMM + attention, per window ===
// LDS layout (shorts):
//  LK  [0,16384)      k  : [head][token 64][32ch]   (frag-ready, 32-short rows)
//  LQ  [16384,32768)  q  : [head][token 64][32ch]   (scaled)
//  LV  [32768,49152)  v^T: [head][jchunk 2][d 32][32 j]
//  U1  [49152,61440)  B staging 3x4096 | later per-wave cb slice (4x2408)
//  U2  [61440,77824)  h (A, k-chunked [kk 8][row 64][32]) | later sp 4x4096
#define LK_  0
#define LQ_  16384
#define LV_  32768
#define U1_  49152
#define U2_  61440

__global__ __launch_bounds__(256, 1) void qkvattn_k(
    const float* __restrict__ x, const float* __restrict__ n1g,
    const float* __restrict__ n1b, const unsigned short* __restrict__ qw,
    const float* __restrict__ qkvb, const unsigned short* __restrict__ cbt,
    unsigned short* __restrict__ ob)
{
    __shared__ __align__(16) unsigned short sm[77824];   // 155,648 B
    const int tid = threadIdx.x, bw = blockIdx.x;
    const int wave = tid >> 6, lane = tid & 63, quad = lane >> 4, l16 = lane & 15;
    const int b = bw >> 6, wi = bw & 63;

    // ---- phase 1: gather 49 shifted tokens, LN1, write h (zero-pad to 64) ----
    {
        const float4 gg = *(const float4*)(n1g + lane * 4);
        const float4 bb = *(const float4*)(n1b + lane * 4);
        #pragma unroll
        for (int g = 0; g < 4; ++g) {
            float4 vv[4];
            #pragma unroll
            for (int j = 0; j < 4; ++j) {
                int row = wave * 16 + g * 4 + j;
                if (row < NN) {
                    int sh_ = (wi >> 3) * WS_ + row / WS_;
                    int sw_ = (wi & 7) * WS_ + row % WS_;
                    int ph = sh_ + SS_; if (ph >= HH)  ph -= HH;
                    int pw = sw_ + SS_; if (pw >= WWI) pw -= WWI;
                    vv[j] = *(const float4*)(x + ((size_t)b * 3136 + ph * 56 + pw) * C_ + lane * 4);
                } else { vv[j].x = vv[j].y = vv[j].z = vv[j].w = 0.0f; }
            }
            #pragma unroll
            for (int j = 0; j < 4; ++j) {
                int row = wave * 16 + g * 4 + j;
                float4 v = vv[j];
                float s = v.x + v.y + v.z + v.w;
                float q2 = v.x*v.x + v.y*v.y + v.z*v.z + v.w*v.w;
                #pragma unroll
                for (int o = 32; o > 0; o >>= 1) { s += __shfl_xor(s, o, 64); q2 += __shfl_xor(q2, o, 64); }
                float mu = s * (1.0f / C_), var = q2 * (1.0f / C_) - mu * mu;
                float rs = rsqrtf(var + EPS_);
                float y0 = (v.x - mu) * rs * gg.x + bb.x;
                float y1 = (v.y - mu) * rs * gg.y + bb.y;
                float y2 = (v.z - mu) * rs * gg.z + bb.z;
                float y3 = (v.w - mu) * rs * gg.w + bb.w;
                if (row >= NN) { y0 = y1 = y2 = y3 = 0.0f; }
                unsigned int lo = (unsigned int)f2bf(y0) | ((unsigned int)f2bf(y1) << 16);
                unsigned int hi = (unsigned int)f2bf(y2) | ((unsigned int)f2bf(y3) << 16);
                uint2 u; u.x = lo; u.y = hi;
                // h chunked: [cc=ch/32][row][ch&31]; lane covers ch 4l..4l+3
                *(uint2*)&sm[U2_ + (lane >> 3) * 2048 + row * 32 + (lane & 7) * 4] = u;
            }
        }
    }
    __syncthreads();

    // ---- phase 2: QKV GEMM, 48-iter (6 n-tiles x 8 k) depth-2 B-stream ----
    f32x4 aq[6][4][2] = {};
    {
        const int r0b = tid >> 2, c0b = (tid & 3) * 8;
        const int woff = wave * 512;
        // pre-issue it=0,1
        #pragma unroll
        for (int p = 0; p < 2; ++p) {
            const unsigned short* src = qw + (size_t)(0 * 128 + r0b) * C_ + p * 32 + c0b;
            unsigned short* d0 = sm + U1_ + p * 4096 + woff;
            gload_lds16(src, d0);
            gload_lds16(src + 64 * C_, d0 + 2048);
        }
        #pragma unroll
        for (int nt6 = 0; nt6 < 6; ++nt6) {
            #pragma unroll
            for (int kk = 0; kk < 8; ++kk) {
                const int it = nt6 * 8 + kk;
                if (it + 2 < 48) {
                    const int nt2 = (it + 2) >> 3, kk2 = (it + 2) & 7;
                    const unsigned short* src = qw + (size_t)(nt2 * 128 + r0b) * C_ + kk2 * 32 + c0b;
                    unsigned short* d0 = sm + U1_ + ((it + 2) % 3) * 4096 + woff;
                    gload_lds16(src, d0);
                    gload_lds16(src + 64 * C_, d0 + 2048);
                    __asm volatile("s_waitcnt vmcnt(4)\n\ts_barrier" ::: "memory");
                } else if (it + 1 < 48) {
                    __asm volatile("s_waitcnt vmcnt(2)\n\ts_barrier" ::: "memory");
                } else {
                    __asm volatile("s_waitcnt vmcnt(0)\n\ts_barrier" ::: "memory");
                }
                const unsigned short* sB = sm + U1_ + (it % 3) * 4096;
                const unsigned short* hA = sm + U2_ + kk * 2048;
                bf16x8 af[4], bf2[2];
                #pragma unroll
                for (int mt = 0; mt < 4; ++mt)
                    af[mt] = __builtin_bit_cast(bf16x8, *(const ushort8v*)(hA + (mt * 16 + l16) * 32 + quad * 8));
                #pragma unroll
                for (int nw = 0; nw < 2; ++nw)
                    bf2[nw] = __builtin_bit_cast(bf16x8, *(const ushort8v*)(sB + (wave * 32 + nw * 16 + l16) * 32 + quad * 8));
                #pragma unroll
                for (int mt = 0; mt < 4; ++mt)
                    #pragma unroll
                    for (int nw = 0; nw < 2; ++nw)
                        aq[nt6][mt][nw] = __builtin_amdgcn_mfma_f32_16x16x32_bf16(af[mt], bf2[nw], aq[nt6][mt][nw], 0, 0, 0);
                __asm volatile("s_barrier" ::: "memory");
            }
        }
    }

    // ---- phase 3: epilogue scatter into q/k/v LDS layouts ----
    #pragma unroll
    for (int nt6 = 0; nt6 < 6; ++nt6) {
        const int seg = nt6 >> 1;              // 0=q 1=k 2=v
        #pragma unroll
        for (int nw = 0; nw < 2; ++nw) {
            const int n = nt6 * 128 + wave * 32 + nw * 16 + l16;   // 0..767
            const float bb = qkvb[n];
            const int nc = n & 255;
            #pragma unroll
            for (int mt = 0; mt < 4; ++mt)
                #pragma unroll
                for (int r = 0; r < 4; ++r) {
                    const int m = mt * 16 + quad * 4 + r;
                    float v = aq[nt6][mt][nw][r] + bb;
                    int addr;
                    if (seg == 0)      { v *= SCALE_; addr = LQ_ + (nc >> 5) * 2048 + m * 32 + (nc & 31); }
                    else if (seg == 1) { addr = LK_ + (nc >> 5) * 2048 + m * 32 + (nc & 31); }
                    else               { addr = LV_ + (nc >> 5) * 2048 + (m >> 5) * 1024 + (nc & 31) * 32 + (m & 31); }
                    sm[addr] = f2bf(v);
                }
        }
    }
    __syncthreads();

    // ---- phase 4: attention, wave-private, 2 heads per wave ----
    const f32x4 zz = {};
    unsigned short* cbW = sm + U1_ + wave * 2408;
    unsigned short* spW = sm + U2_ + wave * 4096;
    #pragma unroll
    for (int hh = 0; hh < 2; ++hh) {
        const int head = wave * 2 + hh;
        const unsigned short* csrc = cbt + (size_t)(wi * 8 + head) * 2408;
        for (int t2 = lane; t2 < 301; t2 += 64)
            *(uint4*)&cbW[t2 * 8] = *(const uint4*)(csrc + t2 * 8);
        __asm volatile("s_waitcnt vmcnt(0) lgkmcnt(0)" ::: "memory");

        // S = q k^T  (M=64, N=64, K=32)
        f32x4 s4[4][4];
        bf16x8 afq[4];
        #pragma unroll
        for (int mt = 0; mt < 4; ++mt)
            afq[mt] = __builtin_bit_cast(bf16x8, *(const ushort8v*)(sm + LQ_ + head * 2048 + (mt * 16 + l16) * 32 + quad * 8));
        #pragma unroll
        for (int jt = 0; jt < 4; ++jt) {
            bf16x8 bk = __builtin_bit_cast(bf16x8, *(const ushort8v*)(sm + LK_ + head * 2048 + (jt * 16 + l16) * 32 + quad * 8));
            #pragma unroll
            for (int mt = 0; mt < 4; ++mt)
                s4[mt][jt] = __builtin_amdgcn_mfma_f32_16x16x32_bf16(afq[mt], bk, zz, 0, 0, 0);
        }
        // softmax rows, write P to sp (A-frag-ready, k-chunked)
        #pragma unroll
        for (int mt = 0; mt < 4; ++mt)
            #pragma unroll
            for (int r = 0; r < 4; ++r) {
                const int i = mt * 16 + quad * 4 + r;
                float vals[4];
                #pragma unroll
                for (int jt = 0; jt < 4; ++jt) {
                    const int j = jt * 16 + l16;
                    vals[jt] = (i < NN && j < NN) ? s4[mt][jt][r] + bf2f(cbW[i * NN + j]) : -1e30f;
                }
                float mx = fmaxf(fmaxf(vals[0], vals[1]), fmaxf(vals[2], vals[3]));
                #pragma unroll
                for (int o = 1; o < 16; o <<= 1) mx = fmaxf(mx, __shfl_xor(mx, o, 64));
                float e[4], sum = 0.0f;
                #pragma unroll
                for (int jt = 0; jt < 4; ++jt) { e[jt] = __expf(vals[jt] - mx); sum += e[jt]; }
                #pragma unroll
                for (int o = 1; o < 16; o <<= 1) sum += __shfl_xor(sum, o, 64);
                const float inv = 1.0f / sum;
                #pragma unroll
                for (int jt = 0; jt < 4; ++jt) {
                    const int j = jt * 16 + l16;
                    spW[(j >> 5) * 2048 + i * 32 + (j & 31)] = f2bf(e[jt] * inv);
                }
            }
        __asm volatile("s_waitcnt lgkmcnt(0)" ::: "memory");

        // O = P V  (M=64, N=32, K=64)
        bf16x8 bv[2][2];
        #pragma unroll
        for (int nt = 0; nt < 2; ++nt)
            #pragma unroll
            for (int kt = 0; kt < 2; ++kt)
                bv[nt][kt] = __builtin_bit_cast(bf16x8, *(const ushort8v*)(sm + LV_ + head * 2048 + kt * 1024 + (nt * 16 + l16) * 32 + quad * 8));
        #pragma unroll
        for (int mt = 0; mt < 4; ++mt) {
            bf16x8 ap0 = __builtin_bit_cast(bf16x8, *(const ushort8v*)(spW + (mt * 16 + l16) * 32 + quad * 8));
            bf16x8 ap1 = __builtin_bit_cast(bf16x8, *(const ushort8v*)(spW + 2048 + (mt * 16 + l16) * 32 + quad * 8));
            #pragma unroll
            for (int nt = 0; nt < 2; ++nt) {
                f32x4 o4 = __builtin_amdgcn_mfma_f32_16x16x32_bf16(ap0, bv[nt][0], zz, 0, 0, 0);
                o4 = __builtin_amdgcn_mfma_f32_16x16x32_bf16(ap1, bv[nt][1], o4, 0, 0, 0);
                #pragma unroll
                for (int r = 0; r < 4; ++r) {
                    const int i = mt * 16 + quad * 4 + r;
                    if (i < NN)
                        ob[((size_t)bw * NN + i) * C_ + head * HD_ + nt * 16 + l16] = f2bf(o4[r]);
                }
            }
        }
    }
}

// ---------------- MFMA GEMM, 128x128 tile, BK=32, depth-3 pipelined DMA ------
template<int EPI, int NT>
__global__ __launch_bounds__(256) void gemm_k(
    const unsigned short* __restrict__ A, const unsigned short* __restrict__ Bt,
    int K, const float* __restrict__ bias,
    const float* __restrict__ resid, float* __restrict__ outF,
    unsigned short* __restrict__ outQ)
{
    __shared__ __align__(16) unsigned char smem[49152];
    const int tid = threadIdx.x;
    const int lin = blockIdx.x;
    const int xcd = lin & 7, t = lin >> 3;
    const int m0 = (xcd * 49 + t / NT) * 128;
    const int n0 = (t % NT) * 128;
    const int wave = tid >> 6, lane = tid & 63, quad = lane >> 4, l16 = lane & 15;
    const int wm = wave >> 1, wn = wave & 1;
    const int r0 = tid >> 2, c0 = (tid & 3) * 8;

    const size_t gA0 = (size_t)(m0 + r0) * K + c0;
    const size_t gA1 = (size_t)(m0 + r0 + 64) * K + c0;
    const size_t gB0 = (size_t)(n0 + r0) * K + c0;
    const size_t gB1 = (size_t)(n0 + r0 + 64) * K + c0;
    const int woff = wave * 512;

    f32x4 acc[4][4] = {};
    const int nk = K >> 5;
    #pragma unroll
    for (int p = 0; p < 2; ++p) {
        unsigned short* sA = (unsigned short*)(smem + p * 16384);
        unsigned short* sB = sA + 4096;
        const int kp = p << 5;
        gload_lds16(A + gA0 + kp, sA + woff);
        gload_lds16(A + gA1 + kp, sA + woff + 2048);
        gload_lds16(Bt + gB0 + kp, sB + woff);
        gload_lds16(Bt + gB1 + kp, sB + woff + 2048);
    }
    int bufc = 0;
    for (int kk = 0; kk < nk; ++kk) {
        if (kk + 2 < nk) {
            int bufn = bufc + 2; if (bufn >= 3) bufn -= 3;
            unsigned short* sA = (unsigned short*)(smem + bufn * 16384);
            unsigned short* sB = sA + 4096;
            const int k2 = (kk + 2) << 5;
            gload_lds16(A + gA0 + k2, sA + woff);
            gload_lds16(A + gA1 + k2, sA + woff + 2048);
            gload_lds16(Bt + gB0 + k2, sB + woff);
            gload_lds16(Bt + gB1 + k2, sB + woff + 2048);
            __asm volatile("s_waitcnt vmcnt(8)\n\ts_barrier" ::: "memory");
        } else if (kk + 1 < nk) {
            __asm volatile("s_waitcnt vmcnt(4)\n\ts_barrier" ::: "memory");
        } else {
            __asm volatile("s_waitcnt vmcnt(0)\n\ts_barrier" ::: "memory");
        }
        const unsigned short* sA = (const unsigned short*)(smem + bufc * 16384);
        const unsigned short* sB = sA + 4096;
        bf16x8 af[4], bfr[4];
        #pragma unroll
        for (int tt = 0; tt < 4; ++tt) {
            af[tt]  = __builtin_bit_cast(bf16x8, *(const ushort8v*)(sA + (wm * 64 + tt * 16 + l16) * 32 + quad * 8));
            bfr[tt] = __builtin_bit_cast(bf16x8, *(const ushort8v*)(sB + (wn * 64 + tt * 16 + l16) * 32 + quad * 8));
        }
        #pragma unroll
        for (int mt = 0; mt < 4; ++mt)
            #pragma unroll
            for (int nt = 0; nt < 4; ++nt)
                acc[mt][nt] = __builtin_amdgcn_mfma_f32_16x16x32_bf16(af[mt], bfr[nt], acc[mt][nt], 0, 0, 0);
        __asm volatile("s_barrier" ::: "memory");
        if (++bufc == 3) bufc = 0;
    }

    float b4[4];
    #pragma unroll
    for (int nt = 0; nt < 4; ++nt) b4[nt] = bias[n0 + wn * 64 + nt * 16 + l16];

    if (EPI == 2) {
        // ---- FC1 + GELU, bf16 out: bounce to LDS, store packed uint4 ----
        unsigned short (*swB)[136] = (unsigned short (*)[136])smem;
        #pragma unroll
        for (int mt = 0; mt < 4; ++mt)
            #pragma unroll
            for (int nt = 0; nt < 4; ++nt)
                #pragma unroll
                for (int r = 0; r < 4; ++r)
                    swB[wm * 64 + mt * 16 + quad * 4 + r][wn * 64 + nt * 16 + l16] =
                        f2bf(gelu_t(acc[mt][nt][r] + b4[nt]));
        __syncthreads();
        for (int tt = tid; tt < 2048; tt += 256) {
            int row = tt >> 4, c8 = (tt & 15) * 8;
            uint4 u = *(uint4*)&swB[row][c8];
            *(uint4*)&outQ[(size_t)(m0 + row) * 1024 + n0 + c8] = u;
        }
    } else {
        // ---- fp32 output: two 64-row passes through LDS, float4 stores ----
        float (*swF)[132] = (float (*)[132])smem;
        #pragma unroll
        for (int p = 0; p < 2; ++p) {
            __syncthreads();
            if (wm == p) {
                #pragma unroll
                for (int mt = 0; mt < 4; ++mt)
                    #pragma unroll
                    for (int nt = 0; nt < 4; ++nt)
                        #pragma unroll
                        for (int r = 0; r < 4; ++r)
                            swF[mt * 16 + quad * 4 + r][wn * 64 + nt * 16 + l16] = acc[mt][nt][r] + b4[nt];
            }
            __syncthreads();
            for (int tt = tid; tt < 2048; tt += 256) {
                int rl = tt >> 5, c4 = (tt & 31) * 4;
                size_t adr;
                if (EPI == 1) {                       // window-reverse + unshift
                    int m = m0 + p * 64 + rl, bw = m / NN, nw = m - bw * NN;
                    int b = bw >> 6, wi = bw & 63;
                    int sh = (wi >> 3) * WS_ + nw / WS_;
                    int sw = (wi & 7) * WS_ + nw % WS_;
                    int ph = sh + SS_; if (ph >= HH)  ph -= HH;
                    int pw = sw + SS_; if (pw >= WWI) pw -= WWI;
                    adr = ((size_t)b * 3136 + ph * 56 + pw) * C_ + n0 + c4;
                } else {
                    adr = (size_t)(m0 + p * 64 + rl) * C_ + n0 + c4;
                }
                float4 u = *(float4*)&swF[rl][c4];
                const float4 rr = (EPI == 1) ? *(const float4*)&resid[adr]
                                             : *(const float4*)&outF[adr];
                u.x += rr.x; u.y += rr.y; u.z += rr.z; u.w += rr.w;
                *(float4*)&outF[adr] = u;
            }
        }
    }
}

extern "C" void kernel_launch(void* const* d_in, const int* in_sizes, int n_in,
                              void* d_out, int out_size, void* d_ws, size_t ws_size,
                              hipStream_t stream)
{
    const float* x     = (const float*)d_in[0];
    const float* mask  = (const float*)d_in[1];
    const float* n1g   = (const float*)d_in[2];
    const float* n1b   = (const float*)d_in[3];
    const float* qkvw  = (const float*)d_in[4];
    const float* qkvb  = (const float*)d_in[5];
    const float* relb  = (const float*)d_in[6];
    const float* projw = (const float*)d_in[7];
    const float* projb = (const float*)d_in[8];
    const float* n2g   = (const float*)d_in[9];
    const float* n2b   = (const float*)d_in[10];
    const float* fc1w  = (const float*)d_in[11];
    const float* fc1b  = (const float*)d_in[12];
    const float* fc2w  = (const float*)d_in[13];
    const float* fc2b  = (const float*)d_in[14];
    float* out = (float*)d_out;

    unsigned short* wq = (unsigned short*)d_ws;   // all weights bf16, contiguous
    unsigned short* wp = wq + 196608;
    unsigned short* w1 = wq + 262144;
    unsigned short* w2 = wq + 524288;
    unsigned short* ob = wq + 786432;             // attn out, windowed (50176,256) bf16
    unsigned short* h2 = ob + 12845056;           // LN2 out (50176,256) bf16
    unsigned short* a1 = h2 + 12845056;           // GELU(fc1) (50176,1024) bf16
    unsigned short* cbt = a1;                     // cb aliases a1 (qkvattn_k finishes before FC1 writes a1)

    convw_k<<<3072, 256, 0, stream>>>(qkvw, projw, fc1w, fc2w, wq);
    cb_k<<<512, 256, 0, stream>>>(mask, relb, cbt);
    qkvattn_k<<<1024, 256, 0, stream>>>(x, n1g, n1b, wq, qkvb, cbt, ob);
    gemm_k<1, 2><<<392 * 2, 256, 0, stream>>>(ob, wp, 256, projb, x, out, nullptr);
    ln_k<<<12544, 256, 0, stream>>>(out, n2g, n2b, h2);
    gemm_k<2, 8><<<392 * 8, 256, 0, stream>>>(h2, w1, 256, fc1b, nullptr, nullptr, a1);
    gemm_k<3, 2><<<392 * 2, 256, 0, stream>>>(a1, w2, 1024, fc2b, nullptr, out, nullptr);
}